// Round 4
// baseline (106.706 us; speedup 1.0000x reference)
//
#include <hip/hip_runtime.h>
#include <math.h>

namespace {
constexpr int   T_STEPS = 400;
constexpr int   HALF    = 200;            // T/2 — scan covers t = 1..200
constexpr int   NPIX    = 250 * 400;      // 100000
constexpr int   NWORDS  = 7;              // packed words cover t in [0, 224)
constexpr int   PRE_BLOCK   = 256;
constexpr int   PXPT        = 8;          // pixels per thread in pre-pass (2 x float4)
constexpr int   PRE_THREADS = NPIX / PXPT;                       // 12500
constexpr int   PRE_NBLK    = (PRE_THREADS + PRE_BLOCK - 1) / PRE_BLOCK;  // 49
constexpr int   REC_BLOCK   = 64;         // one wave: no LDS, no barriers
constexpr int   REC_NBLK    = (NPIX + REC_BLOCK - 1) / REC_BLOCK;         // 1563
constexpr int   NORM_BLOCK  = 256;
constexpr int   NORM_NBLK   = (NPIX + NORM_BLOCK - 1) / NORM_BLOCK;
constexpr float U0 = 0.15f;
}

// order-preserving float <-> uint key (for global atomic min/max)
__device__ __forceinline__ unsigned fkey(float f) {
  const unsigned u = __float_as_uint(f);
  return (u & 0x80000000u) ? ~u : (u | 0x80000000u);
}
__device__ __forceinline__ float funkey(unsigned k) {
  const unsigned u = (k & 0x80000000u) ? (k ^ 0x80000000u) : ~k;
  return __uint_as_float(u);
}

// ---------------- Pass 1: stream spikes -> packed bitmasks ----------------
// Thread owns 8 adjacent pixels; per timestep it loads 2 float4 (32 B/lane,
// 2 KB contiguous per wave-load) and or's one bit into each of 8 register
// words. Output packed[w*NPIX + p]: bit i of word w = spike at t = 32w + i.
__global__ __launch_bounds__(PRE_BLOCK) void pack_spikes(
    const float* __restrict__ spikes, unsigned* __restrict__ packed,
    unsigned* __restrict__ mm) {
  if (blockIdx.x == 0 && blockIdx.y == 0 && threadIdx.x == 0) {
    mm[0] = 0xFFFFFFFFu;   // min slot (uint keys)
    mm[1] = 0u;            // max slot
  }
  const int tid = blockIdx.x * PRE_BLOCK + threadIdx.x;
  if (tid >= PRE_THREADS) return;
  const int w  = blockIdx.y;
  const int px = tid * PXPT;

  unsigned wb[PXPT] = {0u, 0u, 0u, 0u, 0u, 0u, 0u, 0u};
  const size_t rowstart = (size_t)(w * 32) * NPIX + px;
#pragma unroll 8
  for (int t = 0; t < 32; ++t) {
    const float4* rp = reinterpret_cast<const float4*>(spikes + rowstart + (size_t)t * NPIX);
    const float4 a = rp[0];
    const float4 b = rp[1];
    const unsigned bit = 1u << t;
    wb[0] |= (a.x > 0.0f) ? bit : 0u;
    wb[1] |= (a.y > 0.0f) ? bit : 0u;
    wb[2] |= (a.z > 0.0f) ? bit : 0u;
    wb[3] |= (a.w > 0.0f) ? bit : 0u;
    wb[4] |= (b.x > 0.0f) ? bit : 0u;
    wb[5] |= (b.y > 0.0f) ? bit : 0u;
    wb[6] |= (b.z > 0.0f) ? bit : 0u;
    wb[7] |= (b.w > 0.0f) ? bit : 0u;
  }
  uint4* op = reinterpret_cast<uint4*>(packed + (size_t)w * NPIX + px);
  op[0] = make_uint4(wb[0], wb[1], wb[2], wb[3]);
  op[1] = make_uint4(wb[4], wb[5], wb[6], wb[7]);
}

// ---------------- Pass 2: serial recurrence over packed bits ----------------
// R3-verbatim exact math: n recurrence steps with interval d.
__device__ __forceinline__ void apply_segment(float& R, float& u, int d, int n) {
  const float dd = (float)d;
  const float eD = expf(-dd);              // exp(-isi / D), D = 1
  const float eF = expf(-(dd / 10.0f));    // exp(-isi / F), F = 10
  for (int k = 0; k < n; ++k) {
    const float Rn = 1.0f - (1.0f - R * (1.0f - u)) * eD;
    const float un = U0 + (u + 0.15f * (1.0f - u) - U0) * eF;
    R = Rn; u = un;
  }
}

__device__ __forceinline__ void proc_mask(unsigned mask, int t0, int& prev,
                                          float& R, float& u, bool& done) {
  if (done) return;
  while (mask) {
    const int i = __builtin_ctz(mask);
    mask &= mask - 1u;
    const int t = t0 + i;
    if (prev >= 0) {
      const int d = t - prev;
      // t <= HALF: segment (prev, t], endpoint updates only when isi==1
      // t >  HALF: segment clipped to (prev, HALF]
      const int n = (t <= HALF) ? ((d == 1) ? 1 : (d - 1)) : (HALF - prev);
      apply_segment(R, u, d, n);
    }
    prev = t;
    if (t >= HALF) { done = true; return; }
  }
}

__global__ __launch_bounds__(REC_BLOCK) void stp_recur(
    const unsigned* __restrict__ packed, const float* __restrict__ spikes,
    float* __restrict__ img, unsigned* __restrict__ mm) {
  const int  p      = blockIdx.x * REC_BLOCK + threadIdx.x;
  const bool active = (p < NPIX);
  const int  pc     = active ? p : (NPIX - 1);

  bool  done = !active;
  int   prev = -1;
  float R = 1.0f, u = U0;

  unsigned mw[NWORDS];
#pragma unroll
  for (int w = 0; w < NWORDS; ++w) mw[w] = packed[(size_t)w * NPIX + pc];
#pragma unroll
  for (int w = 0; w < NWORDS; ++w) proc_mask(mw[w], w * 32, prev, R, u, done);

  // Rare tail: no spike found in [prev, 224). Exact fallback on raw spikes.
  if (__any(done ? 0 : 1)) {
    const float* spt = spikes + pc;
    for (int t = NWORDS * 32; t < T_STEPS; ++t) {
      if (__all(done ? 1 : 0)) break;
      const float v = spt[(size_t)t * NPIX];
      if (!done && v > 0.0f) {
        if (prev >= 0) apply_segment(R, u, t - prev, HALF - prev);
        prev = t;
        done = true;            // t >= 224 > HALF
      }
    }
  }
  // Lanes never done: trailing steps have isi = inf -> no update. Exact.

  float val = 0.0f;
  if (active) {
    const float lu = logf((u - U0) / (10.0f - U0 + u * 0.85f));
    const float lR = logf((1.0f - R) / (1.0f - R * (1.0f - u)));
    val = (-1.0f / (10.0f * lu)) + (-1.0f / lR);
    img[p] = val;
  }

  // single-wave block: shuffle min/max, then one keyed atomic pair per block
  float vmin = active ? val : INFINITY;
  float vmax = active ? val : -INFINITY;
#pragma unroll
  for (int off = 32; off > 0; off >>= 1) {
    vmin = fminf(vmin, __shfl_down(vmin, off, 64));
    vmax = fmaxf(vmax, __shfl_down(vmax, off, 64));
  }
  if (threadIdx.x == 0) {
    atomicMin(&mm[0], fkey(vmin));
    atomicMax(&mm[1], fkey(vmax));
  }
}

// ---------------- Pass 3: normalize ----------------
__global__ __launch_bounds__(NORM_BLOCK) void normalize_k(
    float* __restrict__ img, const unsigned* __restrict__ mm) {
  const int p = blockIdx.x * NORM_BLOCK + threadIdx.x;
  if (p < NPIX) {
    const float mn = funkey(mm[0]);
    const float mx = funkey(mm[1]);
    const float v  = img[p];
    img[p] = (mx != mn) ? (v - mn) / (mx - mn) : v;
  }
}

extern "C" void kernel_launch(void* const* d_in, const int* in_sizes, int n_in,
                              void* d_out, int out_size, void* d_ws, size_t ws_size,
                              hipStream_t stream) {
  const float* spikes = (const float*)d_in[0];
  float*    out    = (float*)d_out;
  unsigned* mm     = (unsigned*)d_ws;                 // 2 keyed slots
  unsigned* packed = (unsigned*)d_ws + 64;            // 7 * NPIX words (2.8 MB)

  hipLaunchKernelGGL(pack_spikes, dim3(PRE_NBLK, NWORDS), dim3(PRE_BLOCK), 0, stream,
                     spikes, packed, mm);
  hipLaunchKernelGGL(stp_recur, dim3(REC_NBLK), dim3(REC_BLOCK), 0, stream,
                     packed, spikes, out, mm);
  hipLaunchKernelGGL(normalize_k, dim3(NORM_NBLK), dim3(NORM_BLOCK), 0, stream,
                     out, mm);
}